// Round 5
// baseline (467.564 us; speedup 1.0000x reference)
//
#include <hip/hip_runtime.h>
#include <hip/hip_bf16.h>
#include <math.h>

#define B 16
#define N 512
#define L 512
#define DIM 10
#define DM 128
#define H 8
#define DK 16
#define DFF 512
#define LG 3
#define LO 3
#define NEGV -9.0e15f
#define RF 16     // rows per block (ffn/qkv/oproj)
#define AQR 64    // q-rows per attn block

__device__ __forceinline__ float wave_reduce_sum(float v) {
    #pragma unroll
    for (int o = 32; o > 0; o >>= 1) v += __shfl_down(v, o, 64);
    return v;
}

// ---------------- GNN ----------------

__global__ void k_embed_fp(const int* __restrict__ fing, const float* __restrict__ emb_fp,
                           float* __restrict__ xs) {
    int idx = blockIdx.x * blockDim.x + threadIdx.x;
    if (idx >= B * N * DIM) return;
    int d = idx % DIM;
    int bn = idx / DIM;
    xs[idx] = emb_fp[fing[bn] * DIM + d];
}

__global__ void k_gnn_h(const float* __restrict__ xs, const float* __restrict__ fp_mask,
                        const float* __restrict__ Wg, const float* __restrict__ bg,
                        const float* __restrict__ aatt,
                        float* __restrict__ h, float* __restrict__ s1, float* __restrict__ s2) {
    int bn = blockIdx.x * blockDim.x + threadIdx.x;
    if (bn >= B * N) return;
    float x[DIM];
    #pragma unroll
    for (int d = 0; d < DIM; d++) x[d] = xs[bn * DIM + d];
    float m = fp_mask[bn];
    float a1 = 0.f, a2 = 0.f;
    #pragma unroll
    for (int j = 0; j < DIM; j++) {
        float acc = bg[j];
        #pragma unroll
        for (int d = 0; d < DIM; d++) acc += x[d] * Wg[d * DIM + j];
        acc = fmaxf(acc, 0.f) * m;
        h[bn * DIM + j] = acc;
        a1 += acc * aatt[j];
        a2 += acc * aatt[DIM + j];
    }
    s1[bn] = a1;
    s2[bn] = a2;
}

// 16 lane-groups of 16 lanes; each group owns one row. grid = B*(N/16), 256 thr.
__global__ void k_gnn_att(const float* __restrict__ h, const float* __restrict__ s1,
                          const float* __restrict__ s2, const int* __restrict__ adj,
                          float* __restrict__ xs) {
    int b  = blockIdx.x / (N / 16);
    int rg = blockIdx.x % (N / 16);
    int t = threadIdx.x;
    int g  = t >> 4;   // group 0..15
    int ll = t & 15;   // lane in group
    int i = rg * 16 + g;

    __shared__ float h_s[N * DIM];   // 20KB
    __shared__ float s2_s[N];        // 2KB

    const float* hb = h + (long)b * N * DIM;
    for (int idx = t; idx < N * DIM; idx += 256) h_s[idx] = hb[idx];
    for (int j = t; j < N; j += 256) s2_s[j] = s2[b * N + j];
    __syncthreads();

    float s1v = s1[b * N + i];
    const int* adjrow = adj + ((long)b * N + i) * N;

    float e[32];
    #pragma unroll
    for (int c = 0; c < 32; c++) {
        int j = c * 16 + ll;
        float xsc = s1v + s2_s[j];
        xsc = xsc > 0.f ? xsc : 0.01f * xsc;
        e[c] = (adjrow[j] > 0) ? xsc : NEGV;
    }
    float m = e[0];
    #pragma unroll
    for (int c = 1; c < 32; c++) m = fmaxf(m, e[c]);
    #pragma unroll
    for (int off = 1; off < 16; off <<= 1) m = fmaxf(m, __shfl_xor(m, off, 64));

    float sum = 0.f;
    float a[DIM];
    #pragma unroll
    for (int d = 0; d < DIM; d++) a[d] = 0.f;
    #pragma unroll
    for (int c = 0; c < 32; c++) {
        float p = expf(e[c] - m);
        sum += p;
        int j = c * 16 + ll;
        #pragma unroll
        for (int d = 0; d < DIM; d++) a[d] += p * h_s[j * DIM + d];
    }
    #pragma unroll
    for (int off = 1; off < 16; off <<= 1) {
        sum += __shfl_xor(sum, off, 64);
        #pragma unroll
        for (int d = 0; d < DIM; d++) a[d] += __shfl_xor(a[d], off, 64);
    }
    if (ll < DIM) {
        float av = a[0];
        if (ll == 1) av = a[1]; else if (ll == 2) av = a[2]; else if (ll == 3) av = a[3];
        else if (ll == 4) av = a[4]; else if (ll == 5) av = a[5]; else if (ll == 6) av = a[6];
        else if (ll == 7) av = a[7]; else if (ll == 8) av = a[8]; else if (ll == 9) av = a[9];
        xs[((long)b * N + i) * DIM + ll] += av / sum;
    }
}

__global__ void k_compound(const float* __restrict__ xs, const float* __restrict__ fp_mask,
                           const float* __restrict__ Watt, const float* __restrict__ batt,
                           float* __restrict__ compound, float* __restrict__ hc) {
    int b = blockIdx.x;
    int t = threadIdx.x;  // 256
    int wid = t >> 6, lane = t & 63;
    float lacc[DIM];
    #pragma unroll
    for (int d = 0; d < DIM; d++) lacc[d] = 0.f;
    for (int n = t; n < N; n += 256) {
        float m = fp_mask[b * N + n];
        #pragma unroll
        for (int d = 0; d < DIM; d++) lacc[d] += xs[((long)b * N + n) * DIM + d] * m;
    }
    __shared__ float red[4][DIM];
    __shared__ float comp_s[DIM];
    #pragma unroll
    for (int d = 0; d < DIM; d++) lacc[d] = wave_reduce_sum(lacc[d]);
    if (lane == 0) {
        #pragma unroll
        for (int d = 0; d < DIM; d++) red[wid][d] = lacc[d];
    }
    __syncthreads();
    if (t < DIM) {
        float c = (red[0][t] + red[1][t] + red[2][t] + red[3][t]) / (float)N;
        compound[b * DIM + t] = c;
        comp_s[t] = c;
    }
    __syncthreads();
    if (t < DIM) {
        float acc = batt[t];
        #pragma unroll
        for (int e = 0; e < DIM; e++) acc += comp_s[e] * Watt[e * DIM + t];
        hc[b * DIM + t] = fmaxf(acc, 0.f);
    }
}

// ---------------- Transformer ----------------

__global__ void k_pe(float* __restrict__ pe) {
    int idx = blockIdx.x * blockDim.x + threadIdx.x;
    if (idx >= L * DM) return;
    int d = idx % DM, l = idx / DM;
    int k = d >> 1;
    double div = exp((double)(2 * k) * (-log(10000.0) / (double)DM));
    double ang = (double)l * div;
    pe[idx] = (d & 1) ? (float)cos(ang) : (float)sin(ang);
}

__global__ void k_embed_word(const int* __restrict__ words, const float* __restrict__ emb,
                             const float* __restrict__ pe, float* __restrict__ x) {
    long idx = (long)blockIdx.x * blockDim.x + threadIdx.x;
    if (idx >= (long)B * L * DM) return;
    int d = idx % DM;
    long bl = idx / DM;
    int l = (int)(bl % L);
    x[idx] = emb[(long)words[bl] * DM + d] * sqrtf(128.0f) + pe[l * DM + d];
}

__global__ void k_layernorm(const float* __restrict__ x, const float* __restrict__ g,
                            const float* __restrict__ bb, float* __restrict__ out) {
    int row = blockIdx.x;
    int t = threadIdx.x;  // 128
    int wid = t >> 6, lane = t & 63;
    float v = x[(long)row * DM + t];
    float s = wave_reduce_sum(v);
    __shared__ float r2[2], r3[2];
    if (lane == 0) r2[wid] = s;
    __syncthreads();
    float mean = (r2[0] + r2[1]) / (float)DM;
    float dv = v - mean;
    float q = wave_reduce_sum(dv * dv);
    if (lane == 0) r3[wid] = q;
    __syncthreads();
    float sd = sqrtf((r3[0] + r3[1]) / (float)(DM - 1)) + 1e-6f;
    out[(long)row * DM + t] = g[t] * dv / sd + bb[t];
}

// 16 rows per block, 384 threads: thread = (proj, out-col)
__global__ void k_qkv(const float* __restrict__ xn,
                      const float* __restrict__ Wq, const float* __restrict__ bq,
                      const float* __restrict__ Wk, const float* __restrict__ bk,
                      const float* __restrict__ Wv, const float* __restrict__ bv,
                      float* __restrict__ q, float* __restrict__ k, float* __restrict__ v) {
    long row0 = (long)blockIdx.x * RF;
    int t = threadIdx.x;  // 384
    __shared__ float xs_s[RF * DM];
    for (int i = t; i < RF * DM; i += 384) xs_s[i] = xn[row0 * DM + i];
    __syncthreads();
    int proj = t / DM;
    int j = t % DM;
    const float* W    = proj == 0 ? Wq : (proj == 1 ? Wk : Wv);
    const float* bias = proj == 0 ? bq : (proj == 1 ? bk : bv);
    float* out        = proj == 0 ? q  : (proj == 1 ? k  : v);
    float acc[RF];
    #pragma unroll
    for (int r = 0; r < RF; r++) acc[r] = bias[j];
    for (int d = 0; d < DM; d++) {
        float w = W[d * DM + j];
        #pragma unroll
        for (int r = 0; r < RF; r++) acc[r] += xs_s[r * DM + d] * w;
    }
    #pragma unroll
    for (int r = 0; r < RF; r++) {
        long row = row0 + r;
        int b = (int)(row / L), l = (int)(row % L);
        out[(((long)b * H + j / DK) * L + l) * DK + (j % DK)] = acc[r];
    }
}

// flash attention, no LDS: thread = (q-row pair, key-segment of 8).
// Full 16-dim dots per thread (no per-key shuffles); K/V straight from
// global (L1/L2-resident, 8 lines/wave/instr). Softmax merge across the
// 8 seg-lanes once at the end. grid = B*H*(L/AQR), 256 threads.
__global__ void k_attn(const float* __restrict__ q, const float* __restrict__ k,
                       const float* __restrict__ v, const float* __restrict__ wmask,
                       float* __restrict__ attnout) {
    int blk = blockIdx.x;
    int qc = blk % (L / AQR);
    int bh = blk / (L / AQR);
    int b = bh / H, hh = bh % H;
    int t = threadIdx.x;   // 256
    int seg = t & 7;       // 8 key segments x 64 keys
    int pr = t >> 3;       // 0..31 row pairs
    int l0 = qc * AQR + pr * 2;

    const float4* qp = (const float4*)(q + ((long)bh * L + l0) * DK);
    float4 qa0 = qp[0], qa1 = qp[1], qa2 = qp[2], qa3 = qp[3];
    float4 qb0 = qp[4], qb1 = qp[5], qb2 = qp[6], qb3 = qp[7];
    qa0.x*=0.25f;qa0.y*=0.25f;qa0.z*=0.25f;qa0.w*=0.25f;
    qa1.x*=0.25f;qa1.y*=0.25f;qa1.z*=0.25f;qa1.w*=0.25f;
    qa2.x*=0.25f;qa2.y*=0.25f;qa2.z*=0.25f;qa2.w*=0.25f;
    qa3.x*=0.25f;qa3.y*=0.25f;qa3.z*=0.25f;qa3.w*=0.25f;
    qb0.x*=0.25f;qb0.y*=0.25f;qb0.z*=0.25f;qb0.w*=0.25f;
    qb1.x*=0.25f;qb1.y*=0.25f;qb1.z*=0.25f;qb1.w*=0.25f;
    qb2.x*=0.25f;qb2.y*=0.25f;qb2.z*=0.25f;qb2.w*=0.25f;
    qb3.x*=0.25f;qb3.y*=0.25f;qb3.z*=0.25f;qb3.w*=0.25f;

    const float4* kb4 = (const float4*)(k + (long)bh * L * DK);
    const float4* vb4 = (const float4*)(v + (long)bh * L * DK);
    const float4* wm4 = (const float4*)(wmask + (long)b * L);

    float m0 = -1e30f, m1 = -1e30f, ss0 = 0.f, ss1 = 0.f;
    float4 a00 = make_float4(0,0,0,0), a01 = a00, a02 = a00, a03 = a00;
    float4 a10 = a00, a11 = a00, a12 = a00, a13 = a00;

    for (int c = 0; c < 8; c++) {
        int j0 = seg * 64 + c * 8;
        float s0[8], s1[8];
        #pragma unroll
        for (int jj = 0; jj < 8; jj++) {
            const float4* kp = kb4 + (long)(j0 + jj) * 4;
            float4 k0 = kp[0], k1 = kp[1], k2 = kp[2], k3 = kp[3];
            s0[jj] = qa0.x*k0.x + qa0.y*k0.y + qa0.z*k0.z + qa0.w*k0.w
                   + qa1.x*k1.x + qa1.y*k1.y + qa1.z*k1.z + qa1.w*k1.w
                   + qa2.x*k2.x + qa2.y*k2.y + qa2.z*k2.z + qa2.w*k2.w
                   + qa3.x*k3.x + qa3.y*k3.y + qa3.z*k3.z + qa3.w*k3.w;
            s1[jj] = qb0.x*k0.x + qb0.y*k0.y + qb0.z*k0.z + qb0.w*k0.w
                   + qb1.x*k1.x + qb1.y*k1.y + qb1.z*k1.z + qb1.w*k1.w
                   + qb2.x*k2.x + qb2.y*k2.y + qb2.z*k2.z + qb2.w*k2.w
                   + qb3.x*k3.x + qb3.y*k3.y + qb3.z*k3.z + qb3.w*k3.w;
        }
        float4 wma = wm4[j0 / 4], wmb = wm4[j0 / 4 + 1];
        s0[0] = wma.x > 0.f ? s0[0] : -1e9f;  s1[0] = wma.x > 0.f ? s1[0] : -1e9f;
        s0[1] = wma.y > 0.f ? s0[1] : -1e9f;  s1[1] = wma.y > 0.f ? s1[1] : -1e9f;
        s0[2] = wma.z > 0.f ? s0[2] : -1e9f;  s1[2] = wma.z > 0.f ? s1[2] : -1e9f;
        s0[3] = wma.w > 0.f ? s0[3] : -1e9f;  s1[3] = wma.w > 0.f ? s1[3] : -1e9f;
        s0[4] = wmb.x > 0.f ? s0[4] : -1e9f;  s1[4] = wmb.x > 0.f ? s1[4] : -1e9f;
        s0[5] = wmb.y > 0.f ? s0[5] : -1e9f;  s1[5] = wmb.y > 0.f ? s1[5] : -1e9f;
        s0[6] = wmb.z > 0.f ? s0[6] : -1e9f;  s1[6] = wmb.z > 0.f ? s1[6] : -1e9f;
        s0[7] = wmb.w > 0.f ? s0[7] : -1e9f;  s1[7] = wmb.w > 0.f ? s1[7] : -1e9f;

        float cm0 = fmaxf(fmaxf(fmaxf(s0[0],s0[1]),fmaxf(s0[2],s0[3])),
                          fmaxf(fmaxf(s0[4],s0[5]),fmaxf(s0[6],s0[7])));
        float cm1 = fmaxf(fmaxf(fmaxf(s1[0],s1[1]),fmaxf(s1[2],s1[3])),
                          fmaxf(fmaxf(s1[4],s1[5]),fmaxf(s1[6],s1[7])));
        float mn0 = fmaxf(m0, cm0), mn1 = fmaxf(m1, cm1);
        float sc0 = __expf(m0 - mn0), sc1 = __expf(m1 - mn1);
        ss0 *= sc0; ss1 *= sc1;
        a00.x*=sc0;a00.y*=sc0;a00.z*=sc0;a00.w*=sc0;
        a01.x*=sc0;a01.y*=sc0;a01.z*=sc0;a01.w*=sc0;
        a02.x*=sc0;a02.y*=sc0;a02.z*=sc0;a02.w*=sc0;
        a03.x*=sc0;a03.y*=sc0;a03.z*=sc0;a03.w*=sc0;
        a10.x*=sc1;a10.y*=sc1;a10.z*=sc1;a10.w*=sc1;
        a11.x*=sc1;a11.y*=sc1;a11.z*=sc1;a11.w*=sc1;
        a12.x*=sc1;a12.y*=sc1;a12.z*=sc1;a12.w*=sc1;
        a13.x*=sc1;a13.y*=sc1;a13.z*=sc1;a13.w*=sc1;
        m0 = mn0; m1 = mn1;

        #pragma unroll
        for (int jj = 0; jj < 8; jj++) {
            float p0 = __expf(s0[jj] - m0);
            float p1 = __expf(s1[jj] - m1);
            ss0 += p0; ss1 += p1;
            const float4* vp = vb4 + (long)(j0 + jj) * 4;
            float4 v0 = vp[0], v1 = vp[1], v2 = vp[2], v3 = vp[3];
            a00.x += p0*v0.x; a00.y += p0*v0.y; a00.z += p0*v0.z; a00.w += p0*v0.w;
            a01.x += p0*v1.x; a01.y += p0*v1.y; a01.z += p0*v1.z; a01.w += p0*v1.w;
            a02.x += p0*v2.x; a02.y += p0*v2.y; a02.z += p0*v2.z; a02.w += p0*v2.w;
            a03.x += p0*v3.x; a03.y += p0*v3.y; a03.z += p0*v3.z; a03.w += p0*v3.w;
            a10.x += p1*v0.x; a10.y += p1*v0.y; a10.z += p1*v0.z; a10.w += p1*v0.w;
            a11.x += p1*v1.x; a11.y += p1*v1.y; a11.z += p1*v1.z; a11.w += p1*v1.w;
            a12.x += p1*v2.x; a12.y += p1*v2.y; a12.z += p1*v2.z; a12.w += p1*v2.w;
            a13.x += p1*v3.x; a13.y += p1*v3.y; a13.z += p1*v3.z; a13.w += p1*v3.w;
        }
    }

    // merge the 8 key-segments (lane bits 0..2)
    #pragma unroll
    for (int off = 1; off <= 4; off <<= 1) {
        float m0o = __shfl_xor(m0, off, 64), m1o = __shfl_xor(m1, off, 64);
        float s0o = __shfl_xor(ss0, off, 64), s1o = __shfl_xor(ss1, off, 64);
        float mn0 = fmaxf(m0, m0o), mn1 = fmaxf(m1, m1o);
        float ea0 = __expf(m0 - mn0), eb0 = __expf(m0o - mn0);
        float ea1 = __expf(m1 - mn1), eb1 = __expf(m1o - mn1);
        ss0 = ss0 * ea0 + s0o * eb0;
        ss1 = ss1 * ea1 + s1o * eb1;
        #define MRG0(f) { float o_ = __shfl_xor(f, off, 64); f = f * ea0 + o_ * eb0; }
        #define MRG1(f) { float o_ = __shfl_xor(f, off, 64); f = f * ea1 + o_ * eb1; }
        MRG0(a00.x) MRG0(a00.y) MRG0(a00.z) MRG0(a00.w)
        MRG0(a01.x) MRG0(a01.y) MRG0(a01.z) MRG0(a01.w)
        MRG0(a02.x) MRG0(a02.y) MRG0(a02.z) MRG0(a02.w)
        MRG0(a03.x) MRG0(a03.y) MRG0(a03.z) MRG0(a03.w)
        MRG1(a10.x) MRG1(a10.y) MRG1(a10.z) MRG1(a10.w)
        MRG1(a11.x) MRG1(a11.y) MRG1(a11.z) MRG1(a11.w)
        MRG1(a12.x) MRG1(a12.y) MRG1(a12.z) MRG1(a12.w)
        MRG1(a13.x) MRG1(a13.y) MRG1(a13.z) MRG1(a13.w)
        #undef MRG0
        #undef MRG1
        m0 = mn0; m1 = mn1;
    }

    // seg lanes 0-3 write row0 slices 0-3; lanes 4-7 write row1 slices 0-3
    int sl = seg & 3, rr = seg >> 2;
    float inv = 1.f / (rr ? ss1 : ss0);
    float4 w4;
    if (rr == 0) w4 = (sl == 0) ? a00 : (sl == 1) ? a01 : (sl == 2) ? a02 : a03;
    else         w4 = (sl == 0) ? a10 : (sl == 1) ? a11 : (sl == 2) ? a12 : a13;
    float4* outp = (float4*)(attnout + ((long)b * L + (l0 + rr)) * DM + hh * DK);
    outp[sl] = make_float4(w4.x * inv, w4.y * inv, w4.z * inv, w4.w * inv);
}

// x += attnout @ Wo + bo ; 16 rows/block, 128 threads
__global__ void k_oproj(const float* __restrict__ attnout, const float* __restrict__ Wo,
                        const float* __restrict__ bo, float* __restrict__ x) {
    long row0 = (long)blockIdx.x * RF;
    int t = threadIdx.x;  // 128
    __shared__ float a_s[RF * DM];
    for (int i = t; i < RF * DM; i += 128) a_s[i] = attnout[row0 * DM + i];
    __syncthreads();
    float acc[RF];
    #pragma unroll
    for (int r = 0; r < RF; r++) acc[r] = bo[t];
    for (int d = 0; d < DM; d++) {
        float w = Wo[d * DM + t];
        #pragma unroll
        for (int r = 0; r < RF; r++) acc[r] += a_s[r * DM + d] * w;
    }
    #pragma unroll
    for (int r = 0; r < RF; r++) x[(row0 + r) * DM + t] += acc[r];
}

// fused FFN: x += relu(xn@W1+b1)@W2+b2 ; 16 rows/block, 512 threads
__global__ void k_ffn(const float* __restrict__ xn, const float* __restrict__ W1,
                      const float* __restrict__ b1, const float* __restrict__ W2,
                      const float* __restrict__ b2, float* __restrict__ x) {
    long row0 = (long)blockIdx.x * RF;
    int t = threadIdx.x;  // 512
    __shared__ float xs_s[RF * DM];    // 8KB
    __shared__ float h_s[RF * DFF];    // 32KB
    for (int i = t; i < RF * DM; i += 512) xs_s[i] = xn[row0 * DM + i];
    __syncthreads();
    {
        float acc[RF];
        #pragma unroll
        for (int r = 0; r < RF; r++) acc[r] = b1[t];
        for (int d = 0; d < DM; d++) {
            float w = W1[d * DFF + t];
            #pragma unroll
            for (int r = 0; r < RF; r++) acc[r] += xs_s[r * DM + d] * w;
        }
        #pragma unroll
        for (int r = 0; r < RF; r++) h_s[r * DFF + t] = fmaxf(acc[r], 0.f);
    }
    __syncthreads();
    int col = t & 127, rq = t >> 7;   // rq uniform per wave
    float acc2[4];
    #pragma unroll
    for (int rr = 0; rr < 4; rr++) acc2[rr] = b2[col];
    for (int f = 0; f < DFF; f++) {
        float w = W2[f * DM + col];
        #pragma unroll
        for (int rr = 0; rr < 4; rr++) acc2[rr] += h_s[(rq * 4 + rr) * DFF + f] * w;
    }
    #pragma unroll
    for (int rr = 0; rr < 4; rr++) x[(row0 + rq * 4 + rr) * DM + col] += acc2[rr];
}

// lnf -> relu -> Wtout -> Watt/relu -> hp ; per row, 128 threads
__global__ void k_lnf_hp(const float* __restrict__ x, const float* __restrict__ g,
                         const float* __restrict__ bb, const float* __restrict__ Wtout,
                         const float* __restrict__ btout, const float* __restrict__ Watt,
                         const float* __restrict__ batt, float* __restrict__ hp) {
    int row = blockIdx.x;
    int t = threadIdx.x;  // 128
    int wid = t >> 6, lane = t & 63;
    float v = x[(long)row * DM + t];
    float s = wave_reduce_sum(v);
    __shared__ float r2[2], r3[2];
    if (lane == 0) r2[wid] = s;
    __syncthreads();
    float mean = (r2[0] + r2[1]) / (float)DM;
    float dv = v - mean;
    float qq = wave_reduce_sum(dv * dv);
    if (lane == 0) r3[wid] = qq;
    __syncthreads();
    float sd = sqrtf((r3[0] + r3[1]) / (float)(DM - 1)) + 1e-6f;
    float xnv = g[t] * dv / sd + bb[t];
    __shared__ float rrelu[DM];
    rrelu[t] = fmaxf(xnv, 0.f);
    __syncthreads();
    __shared__ float wv_s[DIM];
    if (t < DIM) {
        float acc = btout[t];
        for (int d = 0; d < DM; d++) acc += rrelu[d] * Wtout[d * DIM + t];
        wv_s[t] = acc;
    }
    __syncthreads();
    if (t < DIM) {
        float acc = batt[t];
        #pragma unroll
        for (int e = 0; e < DIM; e++) acc += wv_s[e] * Watt[e * DIM + t];
        hp[(long)row * DIM + t] = fmaxf(acc, 0.f);
    }
}

// final: w = tanh(hc . hp_l) ; protein = mean(w * hp) ; 3-layer MLP ; output.
__global__ void k_final(const float* __restrict__ hp, const float* __restrict__ hc,
                        const float* __restrict__ compound, const float* __restrict__ Wout,
                        const float* __restrict__ bout, const float* __restrict__ Wint,
                        const float* __restrict__ bint, float* __restrict__ out) {
    int b = blockIdx.x;
    int t = threadIdx.x;  // 256
    int wid = t >> 6, lane = t & 63;

    __shared__ float wout_s[LO * 2 * DIM * 2 * DIM];  // 1200 floats
    __shared__ float bout_s[LO * 2 * DIM];
    __shared__ float wint_s[2 * DIM * 2];
    __shared__ float bint_s[2];
    __shared__ float hc_s[DIM];
    __shared__ float red[4][DIM];
    __shared__ float cat_s[2 * DIM];
    __shared__ float tmp_s[2 * DIM];

    for (int i = t; i < LO * 2 * DIM * 2 * DIM; i += 256) wout_s[i] = Wout[i];
    for (int i = t; i < LO * 2 * DIM; i += 256) bout_s[i] = bout[i];
    for (int i = t; i < 2 * DIM * 2; i += 256) wint_s[i] = Wint[i];
    if (t < 2) bint_s[t] = bint[t];
    if (t < DIM) hc_s[t] = hc[b * DIM + t];
    __syncthreads();

    float lacc[DIM];
    #pragma unroll
    for (int e = 0; e < DIM; e++) lacc[e] = 0.f;
    for (int l = t; l < L; l += 256) {
        const float* hpl = hp + ((long)b * L + l) * DIM;
        float hv[DIM];
        float dot = 0.f;
        #pragma unroll
        for (int e = 0; e < DIM; e++) { hv[e] = hpl[e]; dot += hc_s[e] * hv[e]; }
        float w = tanhf(dot);
        #pragma unroll
        for (int e = 0; e < DIM; e++) lacc[e] += w * hv[e];
    }
    #pragma unroll
    for (int e = 0; e < DIM; e++) lacc[e] = wave_reduce_sum(lacc[e]);
    if (lane == 0) {
        #pragma unroll
        for (int e = 0; e < DIM; e++) red[wid][e] = lacc[e];
    }
    __syncthreads();
    if (t < DIM) {
        cat_s[t] = compound[b * DIM + t];
        cat_s[DIM + t] = (red[0][t] + red[1][t] + red[2][t] + red[3][t]) / (float)L;
    }
    __syncthreads();

    for (int j = 0; j < LO; j++) {
        float acc = 0.f;
        if (t < 2 * DIM) {
            acc = bout_s[j * 2 * DIM + t];
            #pragma unroll
            for (int e = 0; e < 2 * DIM; e++)
                acc += cat_s[e] * wout_s[j * 2 * DIM * 2 * DIM + e * 2 * DIM + t];
            acc = fmaxf(acc, 0.f);
            tmp_s[t] = acc;
        }
        __syncthreads();
        if (t < 2 * DIM) cat_s[t] = tmp_s[t];
        __syncthreads();
    }
    if (t < 2) {
        float o = bint_s[t];
        #pragma unroll
        for (int e = 0; e < 2 * DIM; e++) o += cat_s[e] * wint_s[e * 2 + t];
        out[b * 2 + t] = o;
    }
}

extern "C" void kernel_launch(void* const* d_in, const int* in_sizes, int n_in,
                              void* d_out, int out_size, void* d_ws, size_t ws_size,
                              hipStream_t stream) {
    (void)in_sizes; (void)n_in; (void)out_size; (void)ws_size;
    const int*   fingerprints = (const int*)d_in[0];
    const float* fp_mask      = (const float*)d_in[1];
    const int*   adjacency    = (const int*)d_in[2];
    const int*   words        = (const int*)d_in[3];
    const float* words_mask   = (const float*)d_in[4];
    const float* emb_fp       = (const float*)d_in[5];
    const float* emb_word     = (const float*)d_in[6];
    const float* Wg   = (const float*)d_in[7];
    const float* bg   = (const float*)d_in[8];
    const float* attn_a = (const float*)d_in[9];
    const float* Wq = (const float*)d_in[10];
    const float* bq = (const float*)d_in[11];
    const float* Wk = (const float*)d_in[12];
    const float* bk = (const float*)d_in[13];
    const float* Wv = (const float*)d_in[14];
    const float* bv = (const float*)d_in[15];
    const float* Wo = (const float*)d_in[16];
    const float* bo = (const float*)d_in[17];
    const float* ln1_g = (const float*)d_in[18];
    const float* ln1_b = (const float*)d_in[19];
    const float* ln2_g = (const float*)d_in[20];
    const float* ln2_b = (const float*)d_in[21];
    const float* lnf_g = (const float*)d_in[22];
    const float* lnf_b = (const float*)d_in[23];
    const float* W1 = (const float*)d_in[24];
    const float* b1 = (const float*)d_in[25];
    const float* W2 = (const float*)d_in[26];
    const float* b2 = (const float*)d_in[27];
    const float* Wtout = (const float*)d_in[28];
    const float* btout = (const float*)d_in[29];
    const float* Watt  = (const float*)d_in[30];
    const float* batt  = (const float*)d_in[31];
    const float* Wout  = (const float*)d_in[32];
    const float* bout  = (const float*)d_in[33];
    const float* Wint  = (const float*)d_in[34];
    const float* bint  = (const float*)d_in[35];
    float* out = (float*)d_out;

    float* w = (float*)d_ws;
    float* xs = w;        w += B * N * DIM;
    float* h  = w;        w += B * N * DIM;
    float* s1 = w;        w += B * N;
    float* s2 = w;        w += B * N;
    float* compound = w;  w += B * DIM;
    float* hc = w;        w += B * DIM;
    float* pe = w;        w += L * DM;
    float* x  = w;        w += (long)B * L * DM;
    float* xn = w;        w += (long)B * L * DM;
    float* qb = w;        w += (long)B * H * L * DK;
    float* kb = w;        w += (long)B * H * L * DK;
    float* vb = w;        w += (long)B * H * L * DK;
    float* attnout = w;   w += (long)B * L * DM;
    float* hp = w;        w += (long)B * L * DIM;

    // ---- GNN ----
    k_embed_fp<<<(B * N * DIM + 255) / 256, 256, 0, stream>>>(fingerprints, emb_fp, xs);
    for (int i = 0; i < LG; i++) {
        k_gnn_h<<<(B * N + 255) / 256, 256, 0, stream>>>(
            xs, fp_mask, Wg + i * DIM * DIM, bg + i * DIM, attn_a + i * 2 * DIM, h, s1, s2);
        k_gnn_att<<<B * (N / 16), 256, 0, stream>>>(h, s1, s2, adjacency, xs);
    }
    k_compound<<<B, 256, 0, stream>>>(xs, fp_mask, Watt, batt, compound, hc);

    // ---- Transformer ----
    k_pe<<<(L * DM + 255) / 256, 256, 0, stream>>>(pe);
    k_embed_word<<<(B * L * DM + 255) / 256, 256, 0, stream>>>(words, emb_word, pe, x);
    k_layernorm<<<B * L, DM, 0, stream>>>(x, ln1_g, ln1_b, xn);
    k_qkv<<<B * L / RF, 3 * DM, 0, stream>>>(xn, Wq, bq, Wk, bk, Wv, bv, qb, kb, vb);
    k_attn<<<B * H * (L / AQR), 256, 0, stream>>>(qb, kb, vb, words_mask, attnout);
    k_oproj<<<B * L / RF, DM, 0, stream>>>(attnout, Wo, bo, x);
    k_layernorm<<<B * L, DM, 0, stream>>>(x, ln2_g, ln2_b, xn);
    k_ffn<<<B * L / RF, DFF, 0, stream>>>(xn, W1, b1, W2, b2, x);
    k_lnf_hp<<<B * L, DM, 0, stream>>>(x, lnf_g, lnf_b, Wtout, btout, Watt, batt, hp);
    k_final<<<B, 256, 0, stream>>>(hp, hc, compound, Wout, bout, Wint, bint, out);
}

// Round 6
// 305.003 us; speedup vs baseline: 1.5330x; 1.5330x over previous
//
#include <hip/hip_runtime.h>
#include <hip/hip_bf16.h>
#include <math.h>

#define B 16
#define N 512
#define L 512
#define DIM 10
#define DM 128
#define H 8
#define DK 16
#define DFF 512
#define LG 3
#define LO 3
#define NEGV -9.0e15f
#define RF 16     // rows per block (ffn/qkv/oproj)
#define AQR 64    // q-rows per attn block (= lanes per wave)

__device__ __forceinline__ float wave_reduce_sum(float v) {
    #pragma unroll
    for (int o = 32; o > 0; o >>= 1) v += __shfl_down(v, o, 64);
    return v;
}

// ---------------- GNN ----------------

__global__ void k_embed_fp(const int* __restrict__ fing, const float* __restrict__ emb_fp,
                           float* __restrict__ xs) {
    int idx = blockIdx.x * blockDim.x + threadIdx.x;
    if (idx >= B * N * DIM) return;
    int d = idx % DIM;
    int bn = idx / DIM;
    xs[idx] = emb_fp[fing[bn] * DIM + d];
}

__global__ void k_gnn_h(const float* __restrict__ xs, const float* __restrict__ fp_mask,
                        const float* __restrict__ Wg, const float* __restrict__ bg,
                        const float* __restrict__ aatt,
                        float* __restrict__ h, float* __restrict__ s1, float* __restrict__ s2) {
    int bn = blockIdx.x * blockDim.x + threadIdx.x;
    if (bn >= B * N) return;
    float x[DIM];
    #pragma unroll
    for (int d = 0; d < DIM; d++) x[d] = xs[bn * DIM + d];
    float m = fp_mask[bn];
    float a1 = 0.f, a2 = 0.f;
    #pragma unroll
    for (int j = 0; j < DIM; j++) {
        float acc = bg[j];
        #pragma unroll
        for (int d = 0; d < DIM; d++) acc += x[d] * Wg[d * DIM + j];
        acc = fmaxf(acc, 0.f) * m;
        h[bn * DIM + j] = acc;
        a1 += acc * aatt[j];
        a2 += acc * aatt[DIM + j];
    }
    s1[bn] = a1;
    s2[bn] = a2;
}

// 16 lane-groups of 16 lanes; each group owns one row. grid = B*(N/16), 256 thr.
__global__ void k_gnn_att(const float* __restrict__ h, const float* __restrict__ s1,
                          const float* __restrict__ s2, const int* __restrict__ adj,
                          float* __restrict__ xs) {
    int b  = blockIdx.x / (N / 16);
    int rg = blockIdx.x % (N / 16);
    int t = threadIdx.x;
    int g  = t >> 4;   // group 0..15
    int ll = t & 15;   // lane in group
    int i = rg * 16 + g;

    __shared__ float h_s[N * DIM];   // 20KB
    __shared__ float s2_s[N];        // 2KB

    const float* hb = h + (long)b * N * DIM;
    for (int idx = t; idx < N * DIM; idx += 256) h_s[idx] = hb[idx];
    for (int j = t; j < N; j += 256) s2_s[j] = s2[b * N + j];
    __syncthreads();

    float s1v = s1[b * N + i];
    const int* adjrow = adj + ((long)b * N + i) * N;

    float e[32];
    #pragma unroll
    for (int c = 0; c < 32; c++) {
        int j = c * 16 + ll;
        float xsc = s1v + s2_s[j];
        xsc = xsc > 0.f ? xsc : 0.01f * xsc;
        e[c] = (adjrow[j] > 0) ? xsc : NEGV;
    }
    float m = e[0];
    #pragma unroll
    for (int c = 1; c < 32; c++) m = fmaxf(m, e[c]);
    #pragma unroll
    for (int off = 1; off < 16; off <<= 1) m = fmaxf(m, __shfl_xor(m, off, 64));

    float sum = 0.f;
    float a[DIM];
    #pragma unroll
    for (int d = 0; d < DIM; d++) a[d] = 0.f;
    #pragma unroll
    for (int c = 0; c < 32; c++) {
        float p = expf(e[c] - m);
        sum += p;
        int j = c * 16 + ll;
        #pragma unroll
        for (int d = 0; d < DIM; d++) a[d] += p * h_s[j * DIM + d];
    }
    #pragma unroll
    for (int off = 1; off < 16; off <<= 1) {
        sum += __shfl_xor(sum, off, 64);
        #pragma unroll
        for (int d = 0; d < DIM; d++) a[d] += __shfl_xor(a[d], off, 64);
    }
    if (ll < DIM) {
        float av = a[0];
        if (ll == 1) av = a[1]; else if (ll == 2) av = a[2]; else if (ll == 3) av = a[3];
        else if (ll == 4) av = a[4]; else if (ll == 5) av = a[5]; else if (ll == 6) av = a[6];
        else if (ll == 7) av = a[7]; else if (ll == 8) av = a[8]; else if (ll == 9) av = a[9];
        xs[((long)b * N + i) * DIM + ll] += av / sum;
    }
}

__global__ void k_compound(const float* __restrict__ xs, const float* __restrict__ fp_mask,
                           const float* __restrict__ Watt, const float* __restrict__ batt,
                           float* __restrict__ compound, float* __restrict__ hc) {
    int b = blockIdx.x;
    int t = threadIdx.x;  // 256
    int wid = t >> 6, lane = t & 63;
    float lacc[DIM];
    #pragma unroll
    for (int d = 0; d < DIM; d++) lacc[d] = 0.f;
    for (int n = t; n < N; n += 256) {
        float m = fp_mask[b * N + n];
        #pragma unroll
        for (int d = 0; d < DIM; d++) lacc[d] += xs[((long)b * N + n) * DIM + d] * m;
    }
    __shared__ float red[4][DIM];
    __shared__ float comp_s[DIM];
    #pragma unroll
    for (int d = 0; d < DIM; d++) lacc[d] = wave_reduce_sum(lacc[d]);
    if (lane == 0) {
        #pragma unroll
        for (int d = 0; d < DIM; d++) red[wid][d] = lacc[d];
    }
    __syncthreads();
    if (t < DIM) {
        float c = (red[0][t] + red[1][t] + red[2][t] + red[3][t]) / (float)N;
        compound[b * DIM + t] = c;
        comp_s[t] = c;
    }
    __syncthreads();
    if (t < DIM) {
        float acc = batt[t];
        #pragma unroll
        for (int e = 0; e < DIM; e++) acc += comp_s[e] * Watt[e * DIM + t];
        hc[b * DIM + t] = fmaxf(acc, 0.f);
    }
}

// ---------------- Transformer ----------------

__global__ void k_pe(float* __restrict__ pe) {
    int idx = blockIdx.x * blockDim.x + threadIdx.x;
    if (idx >= L * DM) return;
    int d = idx % DM, l = idx / DM;
    int k = d >> 1;
    double div = exp((double)(2 * k) * (-log(10000.0) / (double)DM));
    double ang = (double)l * div;
    pe[idx] = (d & 1) ? (float)cos(ang) : (float)sin(ang);
}

__global__ void k_embed_word(const int* __restrict__ words, const float* __restrict__ emb,
                             const float* __restrict__ pe, float* __restrict__ x) {
    long idx = (long)blockIdx.x * blockDim.x + threadIdx.x;
    if (idx >= (long)B * L * DM) return;
    int d = idx % DM;
    long bl = idx / DM;
    int l = (int)(bl % L);
    x[idx] = emb[(long)words[bl] * DM + d] * sqrtf(128.0f) + pe[l * DM + d];
}

__global__ void k_layernorm(const float* __restrict__ x, const float* __restrict__ g,
                            const float* __restrict__ bb, float* __restrict__ out) {
    int row = blockIdx.x;
    int t = threadIdx.x;  // 128
    int wid = t >> 6, lane = t & 63;
    float v = x[(long)row * DM + t];
    float s = wave_reduce_sum(v);
    __shared__ float r2[2], r3[2];
    if (lane == 0) r2[wid] = s;
    __syncthreads();
    float mean = (r2[0] + r2[1]) / (float)DM;
    float dv = v - mean;
    float q = wave_reduce_sum(dv * dv);
    if (lane == 0) r3[wid] = q;
    __syncthreads();
    float sd = sqrtf((r3[0] + r3[1]) / (float)(DM - 1)) + 1e-6f;
    out[(long)row * DM + t] = g[t] * dv / sd + bb[t];
}

// 16 rows per block, 384 threads: thread = (proj, out-col)
__global__ void k_qkv(const float* __restrict__ xn,
                      const float* __restrict__ Wq, const float* __restrict__ bq,
                      const float* __restrict__ Wk, const float* __restrict__ bk,
                      const float* __restrict__ Wv, const float* __restrict__ bv,
                      float* __restrict__ q, float* __restrict__ k, float* __restrict__ v) {
    long row0 = (long)blockIdx.x * RF;
    int t = threadIdx.x;  // 384
    __shared__ float xs_s[RF * DM];
    for (int i = t; i < RF * DM; i += 384) xs_s[i] = xn[row0 * DM + i];
    __syncthreads();
    int proj = t / DM;
    int j = t % DM;
    const float* W    = proj == 0 ? Wq : (proj == 1 ? Wk : Wv);
    const float* bias = proj == 0 ? bq : (proj == 1 ? bk : bv);
    float* out        = proj == 0 ? q  : (proj == 1 ? k  : v);
    float acc[RF];
    #pragma unroll
    for (int r = 0; r < RF; r++) acc[r] = bias[j];
    for (int d = 0; d < DM; d++) {
        float w = W[d * DM + j];
        #pragma unroll
        for (int r = 0; r < RF; r++) acc[r] += xs_s[r * DM + d] * w;
    }
    #pragma unroll
    for (int r = 0; r < RF; r++) {
        long row = row0 + r;
        int b = (int)(row / L), l = (int)(row % L);
        out[(((long)b * H + j / DK) * L + l) * DK + (j % DK)] = acc[r];
    }
}

// broadcast-K flash attention. grid = B*H*(L/AQR), 256 threads.
// thread = (q-row = lane 0..63, key-segment = wave 0..3 x 128 keys).
// Every lane of a wave reads the SAME K/V row -> 1 cache line per load
// instruction, broadcast. No LDS in the inner loop; no per-key shuffles.
// Segment partials merged once at the end via LDS.
__global__ void __launch_bounds__(256, 4)
k_attn(const float* __restrict__ q, const float* __restrict__ k,
       const float* __restrict__ v, const float* __restrict__ wmask,
       float* __restrict__ attnout) {
    int blk = blockIdx.x;
    int qc = blk % (L / AQR);
    int bh = blk / (L / AQR);
    int b = bh / H, hh = bh % H;
    int t = threadIdx.x;   // 256
    int lane = t & 63;     // q-row within block
    int wv = t >> 6;       // key segment (128 keys each)
    int l = qc * AQR + lane;

    const float4* qp = (const float4*)(q + ((long)bh * L + l) * DK);
    float4 q0 = qp[0], q1 = qp[1], q2 = qp[2], q3 = qp[3];
    q0.x*=0.25f;q0.y*=0.25f;q0.z*=0.25f;q0.w*=0.25f;
    q1.x*=0.25f;q1.y*=0.25f;q1.z*=0.25f;q1.w*=0.25f;
    q2.x*=0.25f;q2.y*=0.25f;q2.z*=0.25f;q2.w*=0.25f;
    q3.x*=0.25f;q3.y*=0.25f;q3.z*=0.25f;q3.w*=0.25f;

    const float4* kb4 = (const float4*)(k + (long)bh * L * DK);
    const float4* vb4 = (const float4*)(v + (long)bh * L * DK);
    const float4* wm4 = (const float4*)(wmask + (long)b * L);

    float m = -1e30f, ss = 0.f;
    float4 a0 = make_float4(0,0,0,0), a1 = a0, a2 = a0, a3 = a0;

    for (int c = 0; c < 16; c++) {
        int j0 = wv * 128 + c * 8;
        float s8[8];
        #pragma unroll
        for (int jj = 0; jj < 8; jj++) {
            const float4* kp = kb4 + (long)(j0 + jj) * 4;
            float4 k0 = kp[0], k1 = kp[1], k2 = kp[2], k3 = kp[3];
            s8[jj] = q0.x*k0.x + q0.y*k0.y + q0.z*k0.z + q0.w*k0.w
                   + q1.x*k1.x + q1.y*k1.y + q1.z*k1.z + q1.w*k1.w
                   + q2.x*k2.x + q2.y*k2.y + q2.z*k2.z + q2.w*k2.w
                   + q3.x*k3.x + q3.y*k3.y + q3.z*k3.z + q3.w*k3.w;
        }
        float4 wma = wm4[j0 / 4], wmb = wm4[j0 / 4 + 1];
        s8[0] = wma.x > 0.f ? s8[0] : -1e9f;
        s8[1] = wma.y > 0.f ? s8[1] : -1e9f;
        s8[2] = wma.z > 0.f ? s8[2] : -1e9f;
        s8[3] = wma.w > 0.f ? s8[3] : -1e9f;
        s8[4] = wmb.x > 0.f ? s8[4] : -1e9f;
        s8[5] = wmb.y > 0.f ? s8[5] : -1e9f;
        s8[6] = wmb.z > 0.f ? s8[6] : -1e9f;
        s8[7] = wmb.w > 0.f ? s8[7] : -1e9f;

        float cm = fmaxf(fmaxf(fmaxf(s8[0],s8[1]),fmaxf(s8[2],s8[3])),
                         fmaxf(fmaxf(s8[4],s8[5]),fmaxf(s8[6],s8[7])));
        float mn = fmaxf(m, cm);
        float sc = __expf(m - mn);
        ss *= sc;
        a0.x*=sc;a0.y*=sc;a0.z*=sc;a0.w*=sc;
        a1.x*=sc;a1.y*=sc;a1.z*=sc;a1.w*=sc;
        a2.x*=sc;a2.y*=sc;a2.z*=sc;a2.w*=sc;
        a3.x*=sc;a3.y*=sc;a3.z*=sc;a3.w*=sc;
        m = mn;

        #pragma unroll
        for (int jj = 0; jj < 8; jj++) {
            float p = __expf(s8[jj] - m);
            ss += p;
            const float4* vp = vb4 + (long)(j0 + jj) * 4;
            float4 v0 = vp[0], v1 = vp[1], v2 = vp[2], v3 = vp[3];
            a0.x += p*v0.x; a0.y += p*v0.y; a0.z += p*v0.z; a0.w += p*v0.w;
            a1.x += p*v1.x; a1.y += p*v1.y; a1.z += p*v1.z; a1.w += p*v1.w;
            a2.x += p*v2.x; a2.y += p*v2.y; a2.z += p*v2.z; a2.w += p*v2.w;
            a3.x += p*v3.x; a3.y += p*v3.y; a3.z += p*v3.z; a3.w += p*v3.w;
        }
    }

    // merge 4 segment partials via LDS (waves 1-3 publish, wave 0 merges)
    __shared__ float part[3][AQR][18];   // 13.8 KB
    if (wv > 0) {
        float* p_ = &part[wv - 1][lane][0];
        p_[0] = m;    p_[1] = ss;
        p_[2] = a0.x; p_[3] = a0.y; p_[4]  = a0.z; p_[5]  = a0.w;
        p_[6] = a1.x; p_[7] = a1.y; p_[8]  = a1.z; p_[9]  = a1.w;
        p_[10]= a2.x; p_[11]= a2.y; p_[12] = a2.z; p_[13] = a2.w;
        p_[14]= a3.x; p_[15]= a3.y; p_[16] = a3.z; p_[17] = a3.w;
    }
    __syncthreads();
    if (wv == 0) {
        for (int s = 0; s < 3; s++) {
            const float* p_ = &part[s][lane][0];
            float m2 = p_[0], ss2 = p_[1];
            float mn = fmaxf(m, m2);
            float ea = __expf(m - mn), eb = __expf(m2 - mn);
            ss = ss * ea + ss2 * eb;
            a0.x = a0.x*ea + p_[2]*eb;  a0.y = a0.y*ea + p_[3]*eb;
            a0.z = a0.z*ea + p_[4]*eb;  a0.w = a0.w*ea + p_[5]*eb;
            a1.x = a1.x*ea + p_[6]*eb;  a1.y = a1.y*ea + p_[7]*eb;
            a1.z = a1.z*ea + p_[8]*eb;  a1.w = a1.w*ea + p_[9]*eb;
            a2.x = a2.x*ea + p_[10]*eb; a2.y = a2.y*ea + p_[11]*eb;
            a2.z = a2.z*ea + p_[12]*eb; a2.w = a2.w*ea + p_[13]*eb;
            a3.x = a3.x*ea + p_[14]*eb; a3.y = a3.y*ea + p_[15]*eb;
            a3.z = a3.z*ea + p_[16]*eb; a3.w = a3.w*ea + p_[17]*eb;
            m = mn;
        }
        float inv = 1.f / ss;
        float4* outp = (float4*)(attnout + ((long)b * L + l) * DM + hh * DK);
        outp[0] = make_float4(a0.x*inv, a0.y*inv, a0.z*inv, a0.w*inv);
        outp[1] = make_float4(a1.x*inv, a1.y*inv, a1.z*inv, a1.w*inv);
        outp[2] = make_float4(a2.x*inv, a2.y*inv, a2.z*inv, a2.w*inv);
        outp[3] = make_float4(a3.x*inv, a3.y*inv, a3.z*inv, a3.w*inv);
    }
}

// x += attnout @ Wo + bo ; 16 rows/block, 128 threads
__global__ void k_oproj(const float* __restrict__ attnout, const float* __restrict__ Wo,
                        const float* __restrict__ bo, float* __restrict__ x) {
    long row0 = (long)blockIdx.x * RF;
    int t = threadIdx.x;  // 128
    __shared__ float a_s[RF * DM];
    for (int i = t; i < RF * DM; i += 128) a_s[i] = attnout[row0 * DM + i];
    __syncthreads();
    float acc[RF];
    #pragma unroll
    for (int r = 0; r < RF; r++) acc[r] = bo[t];
    for (int d = 0; d < DM; d++) {
        float w = Wo[d * DM + t];
        #pragma unroll
        for (int r = 0; r < RF; r++) acc[r] += a_s[r * DM + d] * w;
    }
    #pragma unroll
    for (int r = 0; r < RF; r++) x[(row0 + r) * DM + t] += acc[r];
}

// fused FFN: x += relu(xn@W1+b1)@W2+b2 ; 16 rows/block, 512 threads
__global__ void k_ffn(const float* __restrict__ xn, const float* __restrict__ W1,
                      const float* __restrict__ b1, const float* __restrict__ W2,
                      const float* __restrict__ b2, float* __restrict__ x) {
    long row0 = (long)blockIdx.x * RF;
    int t = threadIdx.x;  // 512
    __shared__ float xs_s[RF * DM];    // 8KB
    __shared__ float h_s[RF * DFF];    // 32KB
    for (int i = t; i < RF * DM; i += 512) xs_s[i] = xn[row0 * DM + i];
    __syncthreads();
    {
        float acc[RF];
        #pragma unroll
        for (int r = 0; r < RF; r++) acc[r] = b1[t];
        for (int d = 0; d < DM; d++) {
            float w = W1[d * DFF + t];
            #pragma unroll
            for (int r = 0; r < RF; r++) acc[r] += xs_s[r * DM + d] * w;
        }
        #pragma unroll
        for (int r = 0; r < RF; r++) h_s[r * DFF + t] = fmaxf(acc[r], 0.f);
    }
    __syncthreads();
    int col = t & 127, rq = t >> 7;   // rq uniform per wave
    float acc2[4];
    #pragma unroll
    for (int rr = 0; rr < 4; rr++) acc2[rr] = b2[col];
    for (int f = 0; f < DFF; f++) {
        float w = W2[f * DM + col];
        #pragma unroll
        for (int rr = 0; rr < 4; rr++) acc2[rr] += h_s[(rq * 4 + rr) * DFF + f] * w;
    }
    #pragma unroll
    for (int rr = 0; rr < 4; rr++) x[(row0 + rq * 4 + rr) * DM + col] += acc2[rr];
}

// lnf -> relu -> Wtout -> Watt/relu -> hp ; per row, 128 threads
__global__ void k_lnf_hp(const float* __restrict__ x, const float* __restrict__ g,
                         const float* __restrict__ bb, const float* __restrict__ Wtout,
                         const float* __restrict__ btout, const float* __restrict__ Watt,
                         const float* __restrict__ batt, float* __restrict__ hp) {
    int row = blockIdx.x;
    int t = threadIdx.x;  // 128
    int wid = t >> 6, lane = t & 63;
    float v = x[(long)row * DM + t];
    float s = wave_reduce_sum(v);
    __shared__ float r2[2], r3[2];
    if (lane == 0) r2[wid] = s;
    __syncthreads();
    float mean = (r2[0] + r2[1]) / (float)DM;
    float dv = v - mean;
    float qq = wave_reduce_sum(dv * dv);
    if (lane == 0) r3[wid] = qq;
    __syncthreads();
    float sd = sqrtf((r3[0] + r3[1]) / (float)(DM - 1)) + 1e-6f;
    float xnv = g[t] * dv / sd + bb[t];
    __shared__ float rrelu[DM];
    rrelu[t] = fmaxf(xnv, 0.f);
    __syncthreads();
    __shared__ float wv_s[DIM];
    if (t < DIM) {
        float acc = btout[t];
        for (int d = 0; d < DM; d++) acc += rrelu[d] * Wtout[d * DIM + t];
        wv_s[t] = acc;
    }
    __syncthreads();
    if (t < DIM) {
        float acc = batt[t];
        #pragma unroll
        for (int e = 0; e < DIM; e++) acc += wv_s[e] * Watt[e * DIM + t];
        hp[(long)row * DIM + t] = fmaxf(acc, 0.f);
    }
}

// final: w = tanh(hc . hp_l) ; protein = mean(w * hp) ; 3-layer MLP ; output.
__global__ void k_final(const float* __restrict__ hp, const float* __restrict__ hc,
                        const float* __restrict__ compound, const float* __restrict__ Wout,
                        const float* __restrict__ bout, const float* __restrict__ Wint,
                        const float* __restrict__ bint, float* __restrict__ out) {
    int b = blockIdx.x;
    int t = threadIdx.x;  // 256
    int wid = t >> 6, lane = t & 63;

    __shared__ float wout_s[LO * 2 * DIM * 2 * DIM];  // 1200 floats
    __shared__ float bout_s[LO * 2 * DIM];
    __shared__ float wint_s[2 * DIM * 2];
    __shared__ float bint_s[2];
    __shared__ float hc_s[DIM];
    __shared__ float red[4][DIM];
    __shared__ float cat_s[2 * DIM];
    __shared__ float tmp_s[2 * DIM];

    for (int i = t; i < LO * 2 * DIM * 2 * DIM; i += 256) wout_s[i] = Wout[i];
    for (int i = t; i < LO * 2 * DIM; i += 256) bout_s[i] = bout[i];
    for (int i = t; i < 2 * DIM * 2; i += 256) wint_s[i] = Wint[i];
    if (t < 2) bint_s[t] = bint[t];
    if (t < DIM) hc_s[t] = hc[b * DIM + t];
    __syncthreads();

    float lacc[DIM];
    #pragma unroll
    for (int e = 0; e < DIM; e++) lacc[e] = 0.f;
    for (int l = t; l < L; l += 256) {
        const float* hpl = hp + ((long)b * L + l) * DIM;
        float hv[DIM];
        float dot = 0.f;
        #pragma unroll
        for (int e = 0; e < DIM; e++) { hv[e] = hpl[e]; dot += hc_s[e] * hv[e]; }
        float w = tanhf(dot);
        #pragma unroll
        for (int e = 0; e < DIM; e++) lacc[e] += w * hv[e];
    }
    #pragma unroll
    for (int e = 0; e < DIM; e++) lacc[e] = wave_reduce_sum(lacc[e]);
    if (lane == 0) {
        #pragma unroll
        for (int e = 0; e < DIM; e++) red[wid][e] = lacc[e];
    }
    __syncthreads();
    if (t < DIM) {
        cat_s[t] = compound[b * DIM + t];
        cat_s[DIM + t] = (red[0][t] + red[1][t] + red[2][t] + red[3][t]) / (float)L;
    }
    __syncthreads();

    for (int j = 0; j < LO; j++) {
        float acc = 0.f;
        if (t < 2 * DIM) {
            acc = bout_s[j * 2 * DIM + t];
            #pragma unroll
            for (int e = 0; e < 2 * DIM; e++)
                acc += cat_s[e] * wout_s[j * 2 * DIM * 2 * DIM + e * 2 * DIM + t];
            acc = fmaxf(acc, 0.f);
            tmp_s[t] = acc;
        }
        __syncthreads();
        if (t < 2 * DIM) cat_s[t] = tmp_s[t];
        __syncthreads();
    }
    if (t < 2) {
        float o = bint_s[t];
        #pragma unroll
        for (int e = 0; e < 2 * DIM; e++) o += cat_s[e] * wint_s[e * 2 + t];
        out[b * 2 + t] = o;
    }
}

extern "C" void kernel_launch(void* const* d_in, const int* in_sizes, int n_in,
                              void* d_out, int out_size, void* d_ws, size_t ws_size,
                              hipStream_t stream) {
    (void)in_sizes; (void)n_in; (void)out_size; (void)ws_size;
    const int*   fingerprints = (const int*)d_in[0];
    const float* fp_mask      = (const float*)d_in[1];
    const int*   adjacency    = (const int*)d_in[2];
    const int*   words        = (const int*)d_in[3];
    const float* words_mask   = (const float*)d_in[4];
    const float* emb_fp       = (const float*)d_in[5];
    const float* emb_word     = (const float*)d_in[6];
    const float* Wg   = (const float*)d_in[7];
    const float* bg   = (const float*)d_in[8];
    const float* attn_a = (const float*)d_in[9];
    const float* Wq = (const float*)d_in[10];
    const float* bq = (const float*)d_in[11];
    const float* Wk = (const float*)d_in[12];
    const float* bk = (const float*)d_in[13];
    const float* Wv = (const float*)d_in[14];
    const float* bv = (const float*)d_in[15];
    const float* Wo = (const float*)d_in[16];
    const float* bo = (const float*)d_in[17];
    const float* ln1_g = (const float*)d_in[18];
    const float* ln1_b = (const float*)d_in[19];
    const float* ln2_g = (const float*)d_in[20];
    const float* ln2_b = (const float*)d_in[21];
    const float* lnf_g = (const float*)d_in[22];
    const float* lnf_b = (const float*)d_in[23];
    const float* W1 = (const float*)d_in[24];
    const float* b1 = (const float*)d_in[25];
    const float* W2 = (const float*)d_in[26];
    const float* b2 = (const float*)d_in[27];
    const float* Wtout = (const float*)d_in[28];
    const float* btout = (const float*)d_in[29];
    const float* Watt  = (const float*)d_in[30];
    const float* batt  = (const float*)d_in[31];
    const float* Wout  = (const float*)d_in[32];
    const float* bout  = (const float*)d_in[33];
    const float* Wint  = (const float*)d_in[34];
    const float* bint  = (const float*)d_in[35];
    float* out = (float*)d_out;

    float* w = (float*)d_ws;
    float* xs = w;        w += B * N * DIM;
    float* h  = w;        w += B * N * DIM;
    float* s1 = w;        w += B * N;
    float* s2 = w;        w += B * N;
    float* compound = w;  w += B * DIM;
    float* hc = w;        w += B * DIM;
    float* pe = w;        w += L * DM;
    float* x  = w;        w += (long)B * L * DM;
    float* xn = w;        w += (long)B * L * DM;
    float* qb = w;        w += (long)B * H * L * DK;
    float* kb = w;        w += (long)B * H * L * DK;
    float* vb = w;        w += (long)B * H * L * DK;
    float* attnout = w;   w += (long)B * L * DM;
    float* hp = w;        w += (long)B * L * DIM;

    // ---- GNN ----
    k_embed_fp<<<(B * N * DIM + 255) / 256, 256, 0, stream>>>(fingerprints, emb_fp, xs);
    for (int i = 0; i < LG; i++) {
        k_gnn_h<<<(B * N + 255) / 256, 256, 0, stream>>>(
            xs, fp_mask, Wg + i * DIM * DIM, bg + i * DIM, attn_a + i * 2 * DIM, h, s1, s2);
        k_gnn_att<<<B * (N / 16), 256, 0, stream>>>(h, s1, s2, adjacency, xs);
    }
    k_compound<<<B, 256, 0, stream>>>(xs, fp_mask, Watt, batt, compound, hc);

    // ---- Transformer ----
    k_pe<<<(L * DM + 255) / 256, 256, 0, stream>>>(pe);
    k_embed_word<<<(B * L * DM + 255) / 256, 256, 0, stream>>>(words, emb_word, pe, x);
    k_layernorm<<<B * L, DM, 0, stream>>>(x, ln1_g, ln1_b, xn);
    k_qkv<<<B * L / RF, 3 * DM, 0, stream>>>(xn, Wq, bq, Wk, bk, Wv, bv, qb, kb, vb);
    k_attn<<<B * H * (L / AQR), 256, 0, stream>>>(qb, kb, vb, words_mask, attnout);
    k_oproj<<<B * L / RF, DM, 0, stream>>>(attnout, Wo, bo, x);
    k_layernorm<<<B * L, DM, 0, stream>>>(x, ln2_g, ln2_b, xn);
    k_ffn<<<B * L / RF, DFF, 0, stream>>>(xn, W1, b1, W2, b2, x);
    k_lnf_hp<<<B * L, DM, 0, stream>>>(x, lnf_g, lnf_b, Wtout, btout, Watt, batt, hp);
    k_final<<<B, 256, 0, stream>>>(hp, hc, compound, Wout, bout, Wint, bint, out);
}